// Round 2
// baseline (241.725 us; speedup 1.0000x reference)
//
#include <hip/hip_runtime.h>
#include <hip/hip_bf16.h>

#define BB 16
#define HH 64
#define WW 64
#define CC 128
#define OO 128

typedef __attribute__((ext_vector_type(8))) short bf16x8;
typedef __attribute__((ext_vector_type(4))) float f32x4;

// Kc[ps][di+1][a] = k1[a - 2*di + ps], k1 = (.25,.75,.75,.25)  (derived & hand-verified)
__constant__ float Kc[2][3][3] = {
    {{0.75f, 0.25f, 0.00f}, {0.25f, 0.75f, 0.75f}, {0.00f, 0.00f, 0.25f}},
    {{0.25f, 0.00f, 0.00f}, {0.75f, 0.75f, 0.25f}, {0.00f, 0.25f, 0.75f}},
};

__device__ __forceinline__ unsigned short f2bf(float f) {
    union { float f; unsigned u; } a; a.f = f;
    unsigned r = a.u + 0x7fffu + ((a.u >> 16) & 1u);  // RNE
    return (unsigned short)(r >> 16);
}

// Pack Weff[phase][kstep][nfrag][lane][8] in bf16 MFMA-B fragment order.
// k = kstep*32 + (lane>>4)*8 + j ; (di,dj) = k>>7 ; c = k&127 ; o = nfrag*16 + (lane&15)
__global__ void pack_b_kernel(const float* __restrict__ w, unsigned short* __restrict__ bp) {
    int l  = threadIdx.x;       // 64
    int nf = blockIdx.x;        // 8
    int ks = blockIdx.y;        // 36
    int ph = blockIdx.z;        // 4  (ps*2+pt)
    int ps = ph >> 1, pt = ph & 1;
    int o = nf * 16 + (l & 15);
    int chunk = l >> 4;
    size_t off = ((((size_t)ph * 36 + ks) * 8 + nf) * 64 + l) * 8;
    for (int j = 0; j < 8; ++j) {
        int k = ks * 32 + chunk * 8 + j;
        int didj = k >> 7;
        int c = k & 127;
        int di = didj / 3, dj = didj % 3;
        float acc = 0.f;
        for (int a = 0; a < 3; ++a) {
            float ka = Kc[ps][di][a];
            for (int bq = 0; bq < 3; ++bq) {
                acc += ka * Kc[pt][dj][bq] * w[((a * 3 + bq) * CC + c) * OO + o];
            }
        }
        bp[off + j] = f2bf(acc);
    }
}

// Block: 4x16 input-pixel tile, 4 waves = 4 output phases sharing one LDS x-patch.
__launch_bounds__(256, 2)
__global__ void upconv_kernel(const float* __restrict__ x,
                              const unsigned short* __restrict__ bp,
                              const float* __restrict__ bias,
                              float* __restrict__ out) {
    __shared__ unsigned short xs[6 * 18 * 128];   // 27,648 B, XOR-swizzled

    const int tid = threadIdx.x;
    const int gT0 = blockIdx.x * 16;
    const int gS0 = blockIdx.y * 4;
    const int b   = blockIdx.z;

    // ---- stage x patch (rows gS0-1..gS0+4, cols gT0-1..gT0+16), fp32 -> bf16 ----
    for (int i = tid; i < 6 * 18 * 16; i += 256) {
        int c8  = i & 15;        // 16B chunk of 8 channels
        int rc  = i >> 4;
        int col = rc % 18;
        int r   = rc / 18;
        int gr = gS0 - 1 + r;
        int gc = gT0 - 1 + col;
        float4 v0 = make_float4(0.f, 0.f, 0.f, 0.f);
        float4 v1 = v0;
        if ((unsigned)gr < HH && (unsigned)gc < WW) {
            const float* p = x + (((size_t)b * HH + gr) * WW + gc) * CC + c8 * 8;
            v0 = *(const float4*)p;
            v1 = *(const float4*)(p + 4);
        }
        unsigned short tmp[8];
        tmp[0] = f2bf(v0.x); tmp[1] = f2bf(v0.y); tmp[2] = f2bf(v0.z); tmp[3] = f2bf(v0.w);
        tmp[4] = f2bf(v1.x); tmp[5] = f2bf(v1.y); tmp[6] = f2bf(v1.z); tmp[7] = f2bf(v1.w);
        int byte = (((r * 18 + col) * 128 + c8 * 8) * 2) ^ ((col & 7) << 4);
        *(bf16x8*)((char*)xs + byte) = *(const bf16x8*)tmp;
    }
    __syncthreads();

    const int wid    = tid >> 6;     // wave = phase
    const int l      = tid & 63;
    const int lane15 = l & 15;
    const int chunk  = l >> 4;
    const int ps = wid >> 1, pt = wid & 1;

    f32x4 acc[4][8];
    #pragma unroll
    for (int mi = 0; mi < 4; ++mi)
        #pragma unroll
        for (int ni = 0; ni < 8; ++ni)
            acc[mi][ni] = (f32x4){0.f, 0.f, 0.f, 0.f};

    const bf16x8* bpv = (const bf16x8*)bp + (size_t)wid * 36 * 8 * 64;

    for (int ks = 0; ks < 36; ++ks) {
        int didj = ks >> 2;
        int di = didj / 3, dj = didj % 3;        // 0..2 == offset+1
        int c0 = (ks & 3) * 32 + chunk * 8;
        bf16x8 af[4];
        #pragma unroll
        for (int mi = 0; mi < 4; ++mi) {
            int r   = mi + di;                   // tile row + halo
            int col = lane15 + dj;               // tile col + halo
            int byte = (((r * 18 + col) * 128 + c0) * 2) ^ ((col & 7) << 4);
            af[mi] = *(const bf16x8*)((const char*)xs + byte);
        }
        const bf16x8* bkv = bpv + (size_t)ks * 8 * 64 + l;
        #pragma unroll
        for (int ni = 0; ni < 8; ++ni) {
            bf16x8 bfv = bkv[ni * 64];
            #pragma unroll
            for (int mi = 0; mi < 4; ++mi)
                acc[mi][ni] = __builtin_amdgcn_mfma_f32_16x16x32_bf16(af[mi], bfv, acc[mi][ni], 0, 0, 0);
        }
    }

    // ---- epilogue: C/D layout col=lane&15 (=o), row=(lane>>4)*4+reg (=T within tile row mi)
    #pragma unroll
    for (int ni = 0; ni < 8; ++ni) {
        int o = ni * 16 + lane15;
        float bv = bias[o];
        #pragma unroll
        for (int mi = 0; mi < 4; ++mi) {
            int s = 2 * (gS0 + mi) + ps;
            #pragma unroll
            for (int rg = 0; rg < 4; ++rg) {
                int t = 2 * (gT0 + chunk * 4 + rg) + pt;
                out[(((size_t)b * 128 + s) * 128 + t) * 128 + o] = acc[mi][ni][rg] + bv;
            }
        }
    }
}

extern "C" void kernel_launch(void* const* d_in, const int* in_sizes, int n_in,
                              void* d_out, int out_size, void* d_ws, size_t ws_size,
                              hipStream_t stream) {
    const float* x    = (const float*)d_in[0];
    const float* w    = (const float*)d_in[1];
    const float* bias = (const float*)d_in[2];
    float* out        = (float*)d_out;
    unsigned short* bp = (unsigned short*)d_ws;   // 4*36*8*64*8 bf16 = 1.18 MB

    dim3 gp(8, 36, 4);
    pack_b_kernel<<<gp, 64, 0, stream>>>(w, bp);

    dim3 gm(4, 16, 16);   // (W/16, H/4, B)
    upconv_kernel<<<gm, 256, 0, stream>>>(x, bp, bias, out);
}

// Round 4
// 237.653 us; speedup vs baseline: 1.0171x; 1.0171x over previous
//
#include <hip/hip_runtime.h>
#include <hip/hip_bf16.h>

#define BB 16
#define HH 64
#define WW 64
#define CC 128
#define OO 128

typedef __attribute__((ext_vector_type(8))) short bf16x8;
typedef __attribute__((ext_vector_type(4))) float f32x4;

// Kc[ps][di+1][a] = k1[a - 2*di + ps], k1 = (.25,.75,.75,.25)  (derived & hand-verified)
__constant__ float Kc[2][3][3] = {
    {{0.75f, 0.25f, 0.00f}, {0.25f, 0.75f, 0.75f}, {0.00f, 0.00f, 0.25f}},
    {{0.25f, 0.00f, 0.00f}, {0.75f, 0.75f, 0.25f}, {0.00f, 0.25f, 0.75f}},
};

__device__ __forceinline__ unsigned short f2bf(float f) {
    union { float f; unsigned u; } a; a.f = f;
    unsigned r = a.u + 0x7fffu + ((a.u >> 16) & 1u);  // RNE
    return (unsigned short)(r >> 16);
}

// Pack Weff[phase][kstep][nfrag][lane][8] in bf16 MFMA-B fragment order.
// k = kstep*32 + (lane>>4)*8 + j ; (di,dj) = k>>7 (uniform per block = ks>>2) ;
// c = k&127 ; o = nfrag*16 + (lane&15)
__global__ void pack_b_kernel(const float* __restrict__ w, unsigned short* __restrict__ bp) {
    int l  = threadIdx.x;       // 64
    int nf = blockIdx.x;        // 8
    int ks = blockIdx.y;        // 36
    int ph = blockIdx.z;        // 4  (ps*2+pt)
    int ps = ph >> 1, pt = ph & 1;
    int didj = ks >> 2;         // == (ks*32 + r)>>7 for all r in [0,32)
    int di = didj / 3, dj = didj % 3;
    // hoisted FIR outer-product (block-uniform)
    float kk[3][3];
    #pragma unroll
    for (int a = 0; a < 3; ++a)
        #pragma unroll
        for (int bq = 0; bq < 3; ++bq)
            kk[a][bq] = Kc[ps][di][a] * Kc[pt][dj][bq];

    int o = nf * 16 + (l & 15);
    int chunk = l >> 4;
    int cbase = (ks & 3) * 32 + chunk * 8;
    size_t off = ((((size_t)ph * 36 + ks) * 8 + nf) * 64 + l) * 8;
    #pragma unroll
    for (int j = 0; j < 8; ++j) {
        int c = cbase + j;
        float acc = 0.f;
        #pragma unroll
        for (int a = 0; a < 3; ++a)
            #pragma unroll
            for (int bq = 0; bq < 3; ++bq)
                acc += kk[a][bq] * w[((a * 3 + bq) * CC + c) * OO + o];
        bp[off + j] = f2bf(acc);
    }
}

// Block: 4x16 input-pixel tile, 4 waves = 4 output phases sharing one LDS x-patch.
__launch_bounds__(256, 2)
__global__ void upconv_kernel(const float* __restrict__ x,
                              const unsigned short* __restrict__ bp,
                              const float* __restrict__ bias,
                              float* __restrict__ out) {
    __shared__ unsigned short xs[6 * 18 * 128];   // 27,648 B, XOR-swizzled

    const int tid = threadIdx.x;
    const int gT0 = blockIdx.x * 16;
    const int gS0 = blockIdx.y * 4;
    const int b   = blockIdx.z;

    // ---- stage x patch (rows gS0-1..gS0+4, cols gT0-1..gT0+16), fp32 -> bf16 ----
    for (int i = tid; i < 6 * 18 * 16; i += 256) {
        int c8  = i & 15;        // 16B chunk of 8 channels
        int rc  = i >> 4;
        int col = rc % 18;
        int r   = rc / 18;
        int gr = gS0 - 1 + r;
        int gc = gT0 - 1 + col;
        float4 v0 = make_float4(0.f, 0.f, 0.f, 0.f);
        float4 v1 = v0;
        if ((unsigned)gr < HH && (unsigned)gc < WW) {
            const float* p = x + (((size_t)b * HH + gr) * WW + gc) * CC + c8 * 8;
            v0 = *(const float4*)p;
            v1 = *(const float4*)(p + 4);
        }
        unsigned short tmp[8];
        tmp[0] = f2bf(v0.x); tmp[1] = f2bf(v0.y); tmp[2] = f2bf(v0.z); tmp[3] = f2bf(v0.w);
        tmp[4] = f2bf(v1.x); tmp[5] = f2bf(v1.y); tmp[6] = f2bf(v1.z); tmp[7] = f2bf(v1.w);
        int byte = (((r * 18 + col) * 128 + c8 * 8) * 2) ^ ((col & 7) << 4);
        *(bf16x8*)((char*)xs + byte) = *(const bf16x8*)tmp;
    }
    __syncthreads();

    const int wid    = tid >> 6;     // wave = phase
    const int l      = tid & 63;
    const int lane15 = l & 15;
    const int chunk  = l >> 4;
    const int ps = wid >> 1, pt = wid & 1;

    f32x4 acc[4][8];
    #pragma unroll
    for (int mi = 0; mi < 4; ++mi)
        #pragma unroll
        for (int ni = 0; ni < 8; ++ni)
            acc[mi][ni] = (f32x4){0.f, 0.f, 0.f, 0.f};

    const bf16x8* bpv = (const bf16x8*)bp + (size_t)wid * 36 * 8 * 64;

    // ---- software-pipelined K loop: prefetch B fragments one ks ahead in halves ----
    bf16x8 b0[4];   // current ks, fragments 0..3 (prefetched)
    {
        const bf16x8* bk = bpv + l;
        #pragma unroll
        for (int ni = 0; ni < 4; ++ni) b0[ni] = bk[ni * 64];
    }

    #pragma unroll 4
    for (int ks = 0; ks < 36; ++ks) {
        const bf16x8* bk = bpv + (size_t)ks * 512 + l;
        // issue loads for this ks's second half (covered by first-half MFMAs)
        bf16x8 b1[4];
        #pragma unroll
        for (int ni = 0; ni < 4; ++ni) b1[ni] = bk[(ni + 4) * 64];

        int didj = ks >> 2;
        int di = didj / 3, dj = didj % 3;        // 0..2 == offset+1
        int c0 = (ks & 3) * 32 + chunk * 8;
        bf16x8 af[4];
        #pragma unroll
        for (int mi = 0; mi < 4; ++mi) {
            int r   = mi + di;                   // tile row + halo
            int col = lane15 + dj;               // tile col + halo
            int byte = (((r * 18 + col) * 128 + c0) * 2) ^ ((col & 7) << 4);
            af[mi] = *(const bf16x8*)((const char*)xs + byte);
        }

        // first half MFMAs (consume b0, cover b1 latency)
        #pragma unroll
        for (int ni = 0; ni < 4; ++ni)
            #pragma unroll
            for (int mi = 0; mi < 4; ++mi)
                acc[mi][ni] = __builtin_amdgcn_mfma_f32_16x16x32_bf16(af[mi], b0[ni], acc[mi][ni], 0, 0, 0);

        // prefetch next ks's first half (covered by second-half MFMAs)
        bf16x8 bn[4];
        if (ks + 1 < 36) {
            const bf16x8* bk2 = bpv + (size_t)(ks + 1) * 512 + l;
            #pragma unroll
            for (int ni = 0; ni < 4; ++ni) bn[ni] = bk2[ni * 64];
        }

        // second half MFMAs (consume b1)
        #pragma unroll
        for (int ni = 0; ni < 4; ++ni)
            #pragma unroll
            for (int mi = 0; mi < 4; ++mi)
                acc[mi][ni + 4] = __builtin_amdgcn_mfma_f32_16x16x32_bf16(af[mi], b1[ni], acc[mi][ni + 4], 0, 0, 0);

        #pragma unroll
        for (int ni = 0; ni < 4; ++ni) b0[ni] = bn[ni];
    }

    // ---- epilogue: C/D layout col=lane&15 (=o), row=(lane>>4)*4+reg (=T within tile row mi)
    #pragma unroll
    for (int ni = 0; ni < 8; ++ni) {
        int o = ni * 16 + lane15;
        float bv = bias[o];
        #pragma unroll
        for (int mi = 0; mi < 4; ++mi) {
            int s = 2 * (gS0 + mi) + ps;
            #pragma unroll
            for (int rg = 0; rg < 4; ++rg) {
                int t = 2 * (gT0 + chunk * 4 + rg) + pt;
                __builtin_nontemporal_store(acc[mi][ni][rg] + bv,
                    &out[(((size_t)b * 128 + s) * 128 + t) * 128 + o]);
            }
        }
    }
}

extern "C" void kernel_launch(void* const* d_in, const int* in_sizes, int n_in,
                              void* d_out, int out_size, void* d_ws, size_t ws_size,
                              hipStream_t stream) {
    const float* x    = (const float*)d_in[0];
    const float* w    = (const float*)d_in[1];
    const float* bias = (const float*)d_in[2];
    float* out        = (float*)d_out;
    unsigned short* bp = (unsigned short*)d_ws;   // 4*36*8*64*8 bf16 = 1.18 MB

    dim3 gp(8, 36, 4);
    pack_b_kernel<<<gp, 64, 0, stream>>>(w, bp);

    dim3 gm(4, 16, 16);   // (W/16, H/4, B)
    upconv_kernel<<<gm, 256, 0, stream>>>(x, bp, bias, out);
}